// Round 4
// baseline (466.534 us; speedup 1.0000x reference)
//
#include <hip/hip_runtime.h>
#include <math.h>

// Problem constants: N=8192 rows, T=1024 trials, K=10 options
#define T_TRIALS 1024
#define KOPT     10
#define RPW      6                   // rows per wave (6*10 = 60 of 64 lanes)
#define TI       16                  // trials per LDS tile
#define NTILES   (T_TRIALS / TI)     // 64
#define LSTRIDE  180                 // 160 + 20 pad floats: 180%32=20 -> max 2-way bank aliasing (free)
#define BLOCK    64                  // one wave per block -> NO __syncthreads anywhere

__device__ __forceinline__ float sigmoidf_(float x) { return 1.0f / (1.0f + expf(-x)); }

// One RW update for the option-k chain (branchless; exact f32 reference arithmetic).
#define STEP(ct, rt)                                              \
    {                                                             \
        float pe = ((rt) == (rt)) ? ((rt) - v) : 0.0f;            \
        float lr = (pe >= 0.0f) ? ap : am;                        \
        float vn = fmaf(lr, pe, v);                               \
        v = ((ct) == k) ? vn : v;                                 \
    }

// Single-pass, barrier-free kernel. Each wave owns 6 rows x 10 options; thread
// (u,k) scans all 1024 trials of its chain in a register. Pre-update values are
// staged per 16-trial tile in wave-private LDS (in-order per-wave LDS ops make
// the cross-lane transpose safe without s_barrier), then the wave streams the
// tile out as coalesced float4. No barriers -> no vmcnt(0) store drains; global
// stores pipeline continuously across tiles.
__global__ __launch_bounds__(BLOCK) void rw_fused(
    const int* __restrict__ choices, const float* __restrict__ rewards,
    const float* __restrict__ apP, const float* __restrict__ amP,
    const float* __restrict__ ivP, float* __restrict__ out, int N)
{
    // 7 row-slots: slot 6 is a dummy landing zone for the 4 idle lanes' writes.
    __shared__ float lds[2][(RPW + 1) * LSTRIDE];   // 2*7*180*4 = 10080 B

    const int j = threadIdx.x;        // 0..63
    const int u = j / KOPT;           // 0..6 (u==6 -> lanes 60..63, dummy chain)
    const int k = j - u * KOPT;       // 0..9 (0..3 for dummy lanes)

    int row = blockIdx.x * RPW + (u < RPW ? u : 0);
    if (row >= N) row = N - 1;        // clamp (tail block / dummy lanes)

    const float ap = sigmoidf_(apP[0]);
    const float am = sigmoidf_(amP[0]);
    float v = 100.0f * tanhf(ivP[0]);

    const int4*   c4 = (const int4*)  (choices + (size_t)row * T_TRIALS);
    const float4* r4 = (const float4*)(rewards + (size_t)row * T_TRIALS);

    float* Lw[2] = { &lds[0][u * LSTRIDE + k], &lds[1][u * LSTRIDE + k] };

    // Store assignment: 6 rows x 40 float4 = 240 vectors, 64 lanes x 4 slots.
    int    s_off[4];
    float* s_dst[4];
    bool   s_ok[4];
#pragma unroll
    for (int w = 0; w < 4; ++w) {
        int idx = w * BLOCK + j;              // 0..255
        int uu  = idx / 40;                   // 0..6
        int f4  = idx - uu * 40;              // 0..39
        s_off[w] = uu * LSTRIDE + f4 * 4;     // uu==6 reads dummy slot (allocated)
        int gu   = blockIdx.x * RPW + uu;
        s_ok[w]  = (uu < RPW) && (gu < N);
        if (gu >= N) gu = N - 1;
        s_dst[w] = out + (size_t)gu * T_TRIALS * KOPT + (size_t)f4 * 4;
    }

    // Prefetch tile 0.
    int4   ca0 = c4[0], ca1 = c4[1], ca2 = c4[2], ca3 = c4[3];
    float4 ra0 = r4[0], ra1 = r4[1], ra2 = r4[2], ra3 = r4[3];

    for (int tile = 0; tile < NTILES; ++tile) {
        // Prefetch next tile (wraps harmlessly on the last iteration).
        int nx = ((tile + 1) & (NTILES - 1)) * 4;
        int4   cb0 = c4[nx + 0], cb1 = c4[nx + 1], cb2 = c4[nx + 2], cb3 = c4[nx + 3];
        float4 rb0 = r4[nx + 0], rb1 = r4[nx + 1], rb2 = r4[nx + 2], rb3 = r4[nx + 3];

        // Emit (pre-update) + update, 16 trials into LDS buffer tile&1.
        float* L = Lw[tile & 1];
        L[ 0*KOPT] = v; STEP(ca0.x, ra0.x) L[ 1*KOPT] = v; STEP(ca0.y, ra0.y)
        L[ 2*KOPT] = v; STEP(ca0.z, ra0.z) L[ 3*KOPT] = v; STEP(ca0.w, ra0.w)
        L[ 4*KOPT] = v; STEP(ca1.x, ra1.x) L[ 5*KOPT] = v; STEP(ca1.y, ra1.y)
        L[ 6*KOPT] = v; STEP(ca1.z, ra1.z) L[ 7*KOPT] = v; STEP(ca1.w, ra1.w)
        L[ 8*KOPT] = v; STEP(ca2.x, ra2.x) L[ 9*KOPT] = v; STEP(ca2.y, ra2.y)
        L[10*KOPT] = v; STEP(ca2.z, ra2.z) L[11*KOPT] = v; STEP(ca2.w, ra2.w)
        L[12*KOPT] = v; STEP(ca3.x, ra3.x) L[13*KOPT] = v; STEP(ca3.y, ra3.y)
        L[14*KOPT] = v; STEP(ca3.z, ra3.z) L[15*KOPT] = v; STEP(ca3.w, ra3.w)

        // Wave-private transpose: per-wave LDS ops are in-order, so the reads
        // below see all lanes' writes above. wave_barrier() only pins compiler
        // ordering — it emits no instructions and forces no vmcnt/lgkmcnt drain.
        __builtin_amdgcn_wave_barrier();

        const float* Ls = &lds[tile & 1][0];
#pragma unroll
        for (int w = 0; w < 4; ++w) {
            float4 val = *(const float4*)(Ls + s_off[w]);
            if (s_ok[w]) *(float4*)s_dst[w] = val;
            s_dst[w] += TI * KOPT;            // advance 160 floats to next tile
        }

        __builtin_amdgcn_wave_barrier();      // keep next tile's LDS writes after reads

        ca0 = cb0; ca1 = cb1; ca2 = cb2; ca3 = cb3;
        ra0 = rb0; ra1 = rb1; ra2 = rb2; ra3 = rb3;
    }
}

extern "C" void kernel_launch(void* const* d_in, const int* in_sizes, int n_in,
                              void* d_out, int out_size, void* d_ws, size_t ws_size,
                              hipStream_t stream)
{
    const int*   choices = (const int*)  d_in[0];
    const float* rewards = (const float*)d_in[1];
    const float* ap      = (const float*)d_in[2];
    const float* am      = (const float*)d_in[3];
    const float* iv      = (const float*)d_in[4];
    float* out = (float*)d_out;

    int N    = in_sizes[0] / T_TRIALS;        // 8192
    int grid = (N + RPW - 1) / RPW;           // 1366 one-wave blocks (~5.3 waves/CU)

    rw_fused<<<grid, BLOCK, 0, stream>>>(choices, rewards, ap, am, iv, out, N);
}